// Round 2
// baseline (3124.695 us; speedup 1.0000x reference)
//
#include <hip/hip_runtime.h>
#include <hip/hip_bf16.h>
#include <math.h>

#define BLK 256

// ---------------- degree / CSR build ----------------
__global__ void count_deg_i(const int* __restrict__ dst, int* __restrict__ cnt, int E_) {
    int e = blockIdx.x * BLK + threadIdx.x;
    if (e < E_) atomicAdd(&cnt[dst[e]], 1);
}

__global__ void dinv_from_cnt(const int* __restrict__ cnt, float* __restrict__ dinv, int n) {
    int i = blockIdx.x * BLK + threadIdx.x;
    if (i < n) dinv[i] = rsqrtf((float)cnt[i] + 1.0f);
}

// exclusive scan of cnt[0..n) -> rowptr[0..n], single block of 1024 threads
__global__ void scan_rowptr(const int* __restrict__ cnt, int* __restrict__ rowptr, int n) {
    __shared__ int sums[1024];
    int tid = threadIdx.x;
    int chunk = (n + 1023) >> 10;
    int beg = tid * chunk, end = min(beg + chunk, n);
    int s = 0;
    for (int i = beg; i < end; ++i) s += cnt[i];
    sums[tid] = s;
    __syncthreads();
    for (int off = 1; off < 1024; off <<= 1) {
        int v = (tid >= off) ? sums[tid - off] : 0;
        __syncthreads();
        sums[tid] += v;
        __syncthreads();
    }
    int run = (tid > 0) ? sums[tid - 1] : 0;
    for (int i = beg; i < end; ++i) { rowptr[i] = run; run += cnt[i]; }
    if (tid == 0) rowptr[n] = sums[1023];
}

__global__ void build_csr(const int* __restrict__ ei, int* __restrict__ cursor,
                          int* __restrict__ csr, int E_) {
    int e = blockIdx.x * BLK + threadIdx.x;
    if (e >= E_) return;
    int d = ei[E_ + e];
    int pos = atomicAdd(&cursor[d], 1);
    csr[pos] = ei[e];
}

// ---------------- GEMM: h = x @ W, H=16 ----------------
template <int F>
__global__ void gemm16(const float* __restrict__ x, const float* __restrict__ W,
                       float* __restrict__ out, int n) {
    __shared__ float Ws[F * 16];
    __shared__ float xs[16 * F];
    int tid = threadIdx.x;
    for (int i = tid; i < F * 16; i += BLK) Ws[i] = W[i];
    int row0 = blockIdx.x * 16;
    for (int i = tid; i < 16 * F; i += BLK) {
        int r = i / F, c = i - r * F;
        int gr = row0 + r;
        xs[i] = (gr < n) ? x[(long long)gr * F + c] : 0.0f;
    }
    __syncthreads();
    int r = tid >> 4, c = tid & 15;
    float acc = 0.0f;
#pragma unroll 8
    for (int f = 0; f < F; ++f) acc += xs[r * F + f] * Ws[f * 16 + c];
    int gr = row0 + r;
    if (gr < n) out[gr * 16 + c] = acc;
}

// ---------------- fused gather + epilogue (H=16) ----------------
// out[node,k] = bias[k] + dinv[node] * ( h[node,k]*dinv[node] + sum_{s in N(node)} h[s,k]*dinv[s] )
//             + (add1? relu(add1)+add1 : 0) + (add2? add2 : 0)
__global__ void gather16(const int* __restrict__ rowptr, const int* __restrict__ csr,
                         const float* __restrict__ dinv, const float* __restrict__ hlin,
                         const float* __restrict__ bias,
                         const float* __restrict__ add1, const float* __restrict__ add2,
                         float* __restrict__ out, int n) {
    int t = blockIdx.x * BLK + threadIdx.x;
    int node = t >> 4, k = t & 15;
    if (node >= n) return;
    float dv = dinv[node];
    float acc = hlin[t] * dv;  // self loop (multiplied by dv again below)
    int beg = rowptr[node], end = rowptr[node + 1];
    for (int j = beg; j < end; ++j) {
        int s = csr[j];
        acc += hlin[s * 16 + k] * dinv[s];
    }
    float v = bias[k] + acc * dv;
    if (add1) { float a = add1[t]; v += fmaxf(a, 0.0f) + a; }
    if (add2) v += add2[t];
    out[t] = v;
}

// ---------------- final GEMM: relu(hf) @ We (16 -> 10), padded to 16 cols ----------------
__global__ void gemm_final_pad(const float* __restrict__ hf, const float* __restrict__ We,
                               float* __restrict__ out, int n) {
    __shared__ float Ws[160];
    if (threadIdx.x < 160) Ws[threadIdx.x] = We[threadIdx.x];
    __syncthreads();
    int t = blockIdx.x * BLK + threadIdx.x;
    int node = t >> 4, j = t & 15;
    if (node >= n) return;
    float acc = 0.0f;
    if (j < 10) {
#pragma unroll
        for (int k = 0; k < 16; ++k) acc += fmaxf(hf[node * 16 + k], 0.0f) * Ws[k * 10 + j];
    }
    out[t] = acc;
}

// ---------------- final gather + bias + log_softmax fused ----------------
__global__ void gather_final(const int* __restrict__ rowptr, const int* __restrict__ csr,
                             const float* __restrict__ dinv, const float* __restrict__ h10,
                             const float* __restrict__ be, float* __restrict__ out, int n) {
    int t = blockIdx.x * BLK + threadIdx.x;
    int node = t >> 4, k = t & 15;
    if (node >= n) return;
    float dv = dinv[node];
    float acc = h10[t] * dv;  // padded cols are zero
    int beg = rowptr[node], end = rowptr[node + 1];
    for (int j = beg; j < end; ++j) {
        int s = csr[j];
        acc += h10[s * 16 + k] * dinv[s];
    }
    float v = (k < 10) ? (be[k] + acc * dv) : 0.0f;
    // log_softmax across the 16-lane group (lanes >=10 masked out)
    float vm = (k < 10) ? v : -INFINITY;
#pragma unroll
    for (int w = 8; w >= 1; w >>= 1) vm = fmaxf(vm, __shfl_xor(vm, w, 16));
    float ex = (k < 10) ? __expf(v - vm) : 0.0f;
#pragma unroll
    for (int w = 8; w >= 1; w >>= 1) ex += __shfl_xor(ex, w, 16);
    if (k < 10) out[node * 10 + k] = v - vm - logf(ex);
}

extern "C" void kernel_launch(void* const* d_in, const int* in_sizes, int n_in,
                              void* d_out, int out_size, void* d_ws, size_t ws_size,
                              hipStream_t stream) {
    const float* x_parent = (const float*)d_in[0];
    const float* x_child1 = (const float*)d_in[1];
    const float* x_child2 = (const float*)d_in[2];
    const float* x_fd     = (const float*)d_in[3];
    const int* e_p  = (const int*)d_in[4];
    const int* e_c1 = (const int*)d_in[5];
    const int* e_c2 = (const int*)d_in[6];
    const int* e_fd = (const int*)d_in[7];
    const float* W1 = (const float*)d_in[8];
    const float* b1 = (const float*)d_in[9];
    const float* W2 = (const float*)d_in[10];
    const float* b2 = (const float*)d_in[11];
    const float* W3 = (const float*)d_in[12];
    const float* b3 = (const float*)d_in[13];
    const float* We = (const float*)d_in[14];
    const float* be = (const float*)d_in[15];

    const int n  = in_sizes[0] / 128;   // 100000
    const int E_ = in_sizes[4] / 2;     // 3200000

    float* ws = (float*)d_ws;
    float* dinv = ws;                              // 4n (slot l at dinv + l*n)
    float* hlin = ws + (size_t)4 * n;              // 16n
    float* hA   = hlin + (size_t)16 * n;           // 16n  (hp, later hf)
    float* hc1  = hA   + (size_t)16 * n;           // 16n
    float* hc2  = hc1  + (size_t)16 * n;           // 16n
    int* cnt    = (int*)(hc2 + (size_t)16 * n);    // n
    int* rowptr = cnt + n;                         // n+1
    int* cursor = rowptr + n + 1;                  // n
    int* csr    = cursor + n;                      // E

    const int gN   = (n + BLK - 1) / BLK;
    const int gN16 = (n * 16 + BLK - 1) / BLK;
    const int gE   = (E_ + BLK - 1) / BLK;
    const int gRow = (n + 15) / 16;

    auto build = [&](const int* ei, float* dinv_l) {
        hipMemsetAsync(cnt, 0, (size_t)n * sizeof(int), stream);
        count_deg_i<<<gE, BLK, 0, stream>>>(ei + E_, cnt, E_);
        dinv_from_cnt<<<gN, BLK, 0, stream>>>(cnt, dinv_l, n);
        scan_rowptr<<<1, 1024, 0, stream>>>(cnt, rowptr, n);
        hipMemcpyAsync(cursor, rowptr, (size_t)n * sizeof(int),
                       hipMemcpyDeviceToDevice, stream);
        build_csr<<<gE, BLK, 0, stream>>>(ei, cursor, csr, E_);
    };

    float* dinv_p  = dinv;
    float* dinv_c1 = dinv + (size_t)n;
    float* dinv_c2 = dinv + (size_t)2 * n;
    float* dinv_fd = dinv + (size_t)3 * n;

    // L1: hp = conv(x_parent, e_p, W1, b1)
    build(e_p, dinv_p);
    gemm16<128><<<gRow, BLK, 0, stream>>>(x_parent, W1, hlin, n);
    gather16<<<gN16, BLK, 0, stream>>>(rowptr, csr, dinv_p, hlin, b1, nullptr, nullptr, hA, n);

    // L2: hc1 = conv(x_child1, e_c1, W2, b2) + relu(hp) + hp
    build(e_c1, dinv_c1);
    gemm16<129><<<gRow, BLK, 0, stream>>>(x_child1, W2, hlin, n);
    gather16<<<gN16, BLK, 0, stream>>>(rowptr, csr, dinv_c1, hlin, b2, hA, nullptr, hc1, n);

    // L3: hc2 = conv(x_child2, e_c2, W3, b3) + relu(hc1) + hc1
    build(e_c2, dinv_c2);
    gemm16<130><<<gRow, BLK, 0, stream>>>(x_child2, W3, hlin, n);
    gather16<<<gN16, BLK, 0, stream>>>(rowptr, csr, dinv_c2, hlin, b3, hc1, nullptr, hc2, n);

    // L4: hf = conv(x_fd, e_fd, W2, b2) + relu(hc2) + hc1 + hc2   (hf overwrites hp slot)
    build(e_fd, dinv_fd);
    gemm16<129><<<gRow, BLK, 0, stream>>>(x_fd, W2, hlin, n);
    gather16<<<gN16, BLK, 0, stream>>>(rowptr, csr, dinv_fd, hlin, b2, hc2, hc1, hA, n);

    // L5: out = log_softmax(conv(relu(hf), e_fd, We, be))  -- reuses e_fd CSR from L4
    gemm_final_pad<<<gN16, BLK, 0, stream>>>(hA, We, hlin, n);
    gather_final<<<gN16, BLK, 0, stream>>>(rowptr, csr, dinv_fd, hlin, be, (float*)d_out, n);
}